// Round 15
// baseline (212.976 us; speedup 1.0000x reference)
//
#include <hip/hip_runtime.h>
#include <cstdint>

#define N_IMG 1024
#define D_DIM 512
#define C_CLS 100000
#define C_PAD 100096            // 1564 * 64
#define NPAN 1564               // 64-col B panels
#define SCALE_LN2 92.33248261689366f  // 64 / ln(2)
#define COS_M 0.8775825618903728f
#define SIN_M 0.479425538604203f

typedef __attribute__((ext_vector_type(4))) int int4v;

#define GLD16(g, l) __builtin_amdgcn_global_load_lds( \
    (const __attribute__((address_space(1))) void*)(g), \
    (__attribute__((address_space(3))) void*)(l), 16, 0, 0)

static __device__ __forceinline__ uint pk4(float a, float b, float c, float d,
                                           float qs) {
  int ia = (int)rintf(a * qs), ib = (int)rintf(b * qs);
  int ic = (int)rintf(c * qs), id = (int)rintf(d * qs);
  return (ia & 255) | ((ib & 255) << 8) | ((ic & 255) << 16) | ((id & 255) << 24);
}

static __device__ __forceinline__ int dp8(uint a, uint b) {
  int s = 0;
  #pragma unroll
  for (int i = 0; i < 4; ++i)
    s += (int)(signed char)((a >> (8 * i)) & 255) *
         (int)(signed char)((b >> (8 * i)) & 255);
  return s;
}

// DPP reduction step over 16-lane rows (VALU pipe — no LDS ops)
template <int CTRL>
static __device__ __forceinline__ float dpp_red(float s) {
  int t = __builtin_amdgcn_update_dpp(0, __builtin_bit_cast(int, s),
                                      CTRL, 0xF, 0xF, false);
  return s + __builtin_bit_cast(float, t);
}

// --------------------------- row L2-normalize + symmetric int8 quantization
// (r9-proven producer: one wave per row, row read once, contiguous 2 KB,
// runs at its 256 MB BW floor with 25k independent blocks)
__global__ __launch_bounds__(256) void norm_q(
    const float* __restrict__ src, signed char* __restrict__ dst,
    float* __restrict__ scale, float* __restrict__ inv, int nvalid, int nrows)
{
  int row = blockIdx.x * 4 + (threadIdx.x >> 6);
  int lane = threadIdx.x & 63;
  if (row >= nrows) return;
  if (row >= nvalid) {                 // pad rows: zero q + zero scale
    uint2 z; z.x = 0u; z.y = 0u;
    ((uint2*)(dst + (size_t)row * D_DIM))[lane] = z;
    if (lane == 0) scale[row] = 0.f;
    return;
  }
  const float4* sp = (const float4*)(src + (size_t)row * D_DIM);
  float4 a = sp[2 * lane], b = sp[2 * lane + 1];   // 8 consecutive elements
  float ss = a.x*a.x + a.y*a.y + a.z*a.z + a.w*a.w
           + b.x*b.x + b.y*b.y + b.z*b.z + b.w*b.w;
  float am = fmaxf(fmaxf(fmaxf(fabsf(a.x), fabsf(a.y)),
                         fmaxf(fabsf(a.z), fabsf(a.w))),
                   fmaxf(fmaxf(fabsf(b.x), fabsf(b.y)),
                         fmaxf(fabsf(b.z), fabsf(b.w))));
  #pragma unroll
  for (int off = 1; off < 64; off <<= 1) {
    ss += __shfl_xor(ss, off);
    am = fmaxf(am, __shfl_xor(am, off));
  }
  am = fmaxf(am, 1e-30f);
  float iv = 1.0f / fmaxf(sqrtf(ss), 1e-12f);
  float qs = 127.0f / am;
  if (lane == 0) { inv[row] = iv; scale[row] = am * iv * (1.0f / 127.0f); }
  uint2 o;
  o.x = pk4(a.x, a.y, a.z, a.w, qs);
  o.y = pk4(b.x, b.y, b.z, b.w, qs);
  ((uint2*)(dst + (size_t)row * D_DIM))[lane] = o;
}

// --------------------- i8 GEMM: 64-col B panel in LDS, barrier-free K-loop
// r13 structure, occupancy-optimized: 64-col panels -> acc[4][4] = 64 AGPR,
// live VGPR ~70, launch_bounds(256,3) caps allocator at 170 -> 3 waves/SIMD
// from 3 DIFFERENT blocks (36.5 KB LDS each) -> desynced latency hiding.
// Stage panel once via global_load_lds (one vmcnt(0)+barrier), then zero
// barriers: 4 stripes of 64 rows, kt at unroll 1 with 1-deep A prefetch
// (r13-proven no-spill).
__global__ __launch_bounds__(256, 3) void gemm_fused(
    const signed char* __restrict__ Bg,     // nw_q [C_PAD][512] i8
    const signed char* __restrict__ Aq,     // ne_q [1024][512] i8
    const float* __restrict__ sa_img, const float* __restrict__ sb_w,
    float* __restrict__ partials)
{
  __shared__ __align__(16) signed char Bq[64 * 512];    // 32 KB
  __shared__ float red[1024];                           // 4 KB

  const int tid  = threadIdx.x;
  const int lane = tid & 63;
  const int w    = tid >> 6;            // 0..3
  const int l15  = lane & 15;
  const int l4   = lane >> 4;
  const int bn   = blockIdx.x;

  // ---- stage panel: 8 rounds x 4 KB. LDS linear dest; source pre-swizzled
  // with the involution d ^= ((d>>9)&7)<<4  (row = d>>9, 16B-slot bits 4-6).
  {
    const signed char* src = Bg + (size_t)bn * (64 * 512);
    #pragma unroll
    for (int i = 0; i < 8; ++i) {
      const int dbase = i * 4096 + w * 1024;     // wave-uniform
      const int d = dbase + lane * 16;           // this lane's dest byte
      const int s = d ^ (((d >> 9) & 7) << 4);
      GLD16(src + s, &Bq[dbase]);
    }
  }
  asm volatile("s_waitcnt vmcnt(0)" ::: "memory");
  __syncthreads();                               // the ONLY barrier pre-store

  const char* Bb = (const char*)Bq;
  const int bswz = (l15 & 7) << 4;

  #pragma unroll 1
  for (int st = 0; st < 4; ++st) {               // 4 stripes of 64 rows
    int4v acc[4][4] = {};                        // 64 AGPRs
    const int row0 = w * 256 + st * 64;
    const signed char* arow = Aq + (size_t)(row0 + l15) * D_DIM + l4 * 16;

    int4v afc[4];
    #pragma unroll
    for (int mf = 0; mf < 4; ++mf)
      afc[mf] = *(const int4v*)(arow + mf * 16 * D_DIM);

    #pragma unroll 1
    for (int kt = 0; kt < 8; ++kt) {
      int4v afn[4];
      if (kt < 7) {                              // prefetch next kt early
        #pragma unroll
        for (int mf = 0; mf < 4; ++mf)
          afn[mf] = *(const int4v*)(arow + mf * 16 * D_DIM + (kt + 1) * 64);
      }
      #pragma unroll
      for (int n = 0; n < 4; ++n) {
        const int byt = (((n * 16 + l15) * 512) + kt * 64 + l4 * 16) ^ bswz;
        int4v bf = *(const int4v*)(Bb + byt);
        #pragma unroll
        for (int mf = 0; mf < 4; ++mf)
          acc[mf][n] = __builtin_amdgcn_mfma_i32_16x16x64_i8(
              afc[mf], bf, acc[mf][n], 0, 0, 0);
      }
      if (kt < 7) {
        #pragma unroll
        for (int mf = 0; mf < 4; ++mf) afc[mf] = afn[mf];
      }
    }

    // stripe epilogue: dequant + exp2 + DPP reduce -> red[] (unique rows)
    // C/D layout (m89, dtype-independent): col = l15, row_in_frag = l4*4 + j
    float sb2[4], offc[4];
    #pragma unroll
    for (int n = 0; n < 4; ++n) {
      int gcol = bn * 64 + n * 16 + l15;
      sb2[n]  = sb_w[gcol] * SCALE_LN2;          // sb_w[pad] = 0
      offc[n] = (gcol < C_CLS) ? 0.f : -1e38f;
    }
    #pragma unroll
    for (int mf = 0; mf < 4; ++mf) {
      #pragma unroll
      for (int j = 0; j < 4; ++j) {
        const int row = row0 + mf * 16 + l4 * 4 + j;
        const float sa = sa_img[row];
        float s = 0.f;
        #pragma unroll
        for (int n = 0; n < 4; ++n) {
          float x = (float)acc[mf][n][j] * sa;
          s += __builtin_amdgcn_exp2f(fmaf(x, sb2[n], offc[n]));
        }
        s = dpp_red<0xB1>(s);   // quad_perm xor1
        s = dpp_red<0x4E>(s);   // quad_perm xor2
        s = dpp_red<0x124>(s);  // row_ror:4
        s = dpp_red<0x128>(s);  // row_ror:8
        if (l15 == 0) red[row] = s;
      }
    }
  }
  __syncthreads();
  #pragma unroll
  for (int t = 0; t < 4; ++t)                    // one dense 4 KB store
    partials[(size_t)bn * 1024 + t * 256 + tid] = red[t * 256 + tid];
}

// ---------------------------------------------------------------- zero rows
__global__ void zero_rows(float* p) {
  p[blockIdx.x * 256 + threadIdx.x] = 0.f;
}

// ------------------- row_sums[r] += partials chunk sums (32 blocks, atomic)
__global__ __launch_bounds__(256) void reduce_partials(
    const float* __restrict__ partials, float* __restrict__ row_sums)
{
  const int c = blockIdx.x >> 2;                  // bn-chunk 0..7
  const int gid = (blockIdx.x & 3) * 256 + threadIdx.x;
  const int b0 = c * 196;
  const int b1 = (b0 + 196 < NPAN) ? b0 + 196 : NPAN;
  float s = 0.f;
  for (int bn = b0; bn < b1; ++bn)
    s += partials[(size_t)bn * 1024 + gid];
  atomicAdd(&row_sums[gid], s);
}

// ---------------------------------------- per-row margin fixup + row loss
// Subtracts the quantized target term BIT-EXACTLY: same i32 dot from the
// stored q-vectors + the identical float expression as the GEMM epilogue.
__global__ __launch_bounds__(256) void fix_loss(
    const float* __restrict__ images, const float* __restrict__ weight,
    const int* __restrict__ labels, const float* __restrict__ img_inv,
    const float* __restrict__ w_inv,
    const signed char* __restrict__ ne_q, const signed char* __restrict__ nw_q,
    const float* __restrict__ sa_img, const float* __restrict__ sb_w,
    const float* __restrict__ row_sums, float* __restrict__ loss_buf)
{
  int row = blockIdx.x * 4 + (threadIdx.x >> 6);
  int lane = threadIdx.x & 63;
  int lab = labels[row];
  const float4* ip = (const float4*)(images + (size_t)row * D_DIM);
  const float4* wp = (const float4*)(weight + (size_t)lab * D_DIM);
  float4 a = ip[lane],       b = wp[lane];
  float4 a2 = ip[lane + 64], b2 = wp[lane + 64];
  float dot = a.x*b.x + a.y*b.y + a.z*b.z + a.w*b.w
            + a2.x*b2.x + a2.y*b2.y + a2.z*b2.z + a2.w*b2.w;
  uint qa0 = ((const uint*)(ne_q + (size_t)row * D_DIM))[lane];
  uint qa1 = ((const uint*)(ne_q + (size_t)row * D_DIM))[64 + lane];
  uint qb0 = ((const uint*)(nw_q + (size_t)lab * D_DIM))[lane];
  uint qb1 = ((const uint*)(nw_q + (size_t)lab * D_DIM))[64 + lane];
  int id = dp8(qa0, qb0) + dp8(qa1, qb1);
  #pragma unroll
  for (int off = 1; off < 64; off <<= 1) {
    dot += __shfl_xor(dot, off);
    id  += __shfl_xor(id, off);
  }
  if (lane == 0) {
    // quantized target logit — identical expression to GEMM epilogue
    float x  = (float)id * sa_img[row];
    float eq = __builtin_amdgcn_exp2f(fmaf(x, sb_w[lab] * SCALE_LN2, 0.f));
    // f32-exact target cosine + ArcFace margin
    float t = dot * img_inv[row] * w_inv[lab];
    t = fminf(fmaxf(t, -1.f), 1.f);
    float tadj = t * COS_M - sqrtf(fmaxf(1.f - t * t, 0.f)) * SIN_M;
    float s = row_sums[row] - eq
            + __builtin_amdgcn_exp2f(tadj * SCALE_LN2);
    loss_buf[row] = logf(s) - 64.f * tadj;
  }
}

// ------------------------------------------------------------ final mean
__global__ void final_reduce(const float* __restrict__ loss_buf,
                             float* __restrict__ out)
{
  __shared__ float sh[16];
  int tid = threadIdx.x;
  float v = loss_buf[tid];
  #pragma unroll
  for (int off = 1; off < 64; off <<= 1) v += __shfl_xor(v, off);
  if ((tid & 63) == 0) sh[tid >> 6] = v;
  __syncthreads();
  if (tid < 16) {
    float w = sh[tid];
    #pragma unroll
    for (int off = 1; off < 16; off <<= 1) w += __shfl_xor(w, off);
    if (tid == 0) out[0] = w * (1.0f / 1024.0f);
  }
}

// ----------------------------------------------------------------- launch
extern "C" void kernel_launch(void* const* d_in, const int* in_sizes, int n_in,
                              void* d_out, int out_size, void* d_ws, size_t ws_size,
                              hipStream_t stream) {
  const float* images = (const float*)d_in[0];
  const int*   labels = (const int*)d_in[1];
  const float* weight = (const float*)d_in[2];
  float* out = (float*)d_out;
  char* ws = (char*)d_ws;

  // workspace layout (512B-aligned offsets)
  float*       row_sums = (float*)(ws + 0);          //  4 KB
  float*       loss_buf = (float*)(ws + 4096);       //  4 KB
  float*       img_inv  = (float*)(ws + 8192);       //  4 KB
  float*       sa_img   = (float*)(ws + 12288);      //  4 KB
  float*       w_inv    = (float*)(ws + 16384);      //  ~400 KB (C_PAD)
  float*       sb_w     = (float*)(ws + 417792);     //  ~400 KB (C_PAD)
  float*       partials = (float*)(ws + 819200);     //  ~6.4 MB [1564][1024]
  signed char* ne_q     = (signed char*)(ws + 7229440);  // 512 KB [1024][512]
  signed char* nw_q     = (signed char*)(ws + 7753728);  // ~51 MB [C_PAD][512]

  norm_q<<<N_IMG / 4, 256, 0, stream>>>(images, ne_q, sa_img, img_inv,
                                        N_IMG, N_IMG);
  norm_q<<<C_PAD / 4, 256, 0, stream>>>(weight, nw_q, sb_w, w_inv,
                                        C_CLS, C_PAD);
  zero_rows<<<4, 256, 0, stream>>>(row_sums);
  gemm_fused<<<NPAN, 256, 0, stream>>>(nw_q, ne_q, sa_img, sb_w, partials);
  reduce_partials<<<32, 256, 0, stream>>>(partials, row_sums);
  fix_loss<<<N_IMG / 4, 256, 0, stream>>>(images, weight, labels, img_inv,
                                          w_inv, ne_q, nw_q, sa_img, sb_w,
                                          row_sums, loss_buf);
  final_reduce<<<1, 1024, 0, stream>>>(loss_buf, out);
}

// Round 16
// 153.074 us; speedup vs baseline: 1.3913x; 1.3913x over previous
//
#include <hip/hip_runtime.h>
#include <cstdint>

#define N_IMG 1024
#define D_DIM 512
#define C_CLS 100000
#define C_PAD 100096            // 782 * 128
#define NPAN 782                // 128-col B panels
#define SCALE_LN2 92.33248261689366f  // 64 / ln(2)
#define COS_M 0.8775825618903728f
#define SIN_M 0.479425538604203f

typedef __attribute__((ext_vector_type(4))) int int4v;

#define GLD16(g, l) __builtin_amdgcn_global_load_lds( \
    (const __attribute__((address_space(1))) void*)(g), \
    (__attribute__((address_space(3))) void*)(l), 16, 0, 0)

static __device__ __forceinline__ uint pk4(float a, float b, float c, float d,
                                           float qs) {
  int ia = (int)rintf(a * qs), ib = (int)rintf(b * qs);
  int ic = (int)rintf(c * qs), id = (int)rintf(d * qs);
  return (ia & 255) | ((ib & 255) << 8) | ((ic & 255) << 16) | ((id & 255) << 24);
}

static __device__ __forceinline__ int dp8(uint a, uint b) {
  int s = 0;
  #pragma unroll
  for (int i = 0; i < 4; ++i)
    s += (int)(signed char)((a >> (8 * i)) & 255) *
         (int)(signed char)((b >> (8 * i)) & 255);
  return s;
}

// DPP reduction step over 16-lane rows (VALU pipe — no LDS ops)
template <int CTRL>
static __device__ __forceinline__ float dpp_red(float s) {
  int t = __builtin_amdgcn_update_dpp(0, __builtin_bit_cast(int, s),
                                      CTRL, 0xF, 0xF, false);
  return s + __builtin_bit_cast(float, t);
}

// --------------------------- row L2-normalize + symmetric int8 quantization
// Optional second output `frag`: fragment-major layout for single-segment
// GEMM A-loads — chunk (g, kt, l4, l15) = A[g*16+l15][kt*64+l4*16 .. +16).
__global__ __launch_bounds__(256) void norm_q(
    const float* __restrict__ src, signed char* __restrict__ dst,
    signed char* __restrict__ frag,
    float* __restrict__ scale, float* __restrict__ inv, int nvalid, int nrows)
{
  int row = blockIdx.x * 4 + (threadIdx.x >> 6);
  int lane = threadIdx.x & 63;
  if (row >= nrows) return;
  if (row >= nvalid) {                 // pad rows: zero q + zero scale
    uint2 z; z.x = 0u; z.y = 0u;
    ((uint2*)(dst + (size_t)row * D_DIM))[lane] = z;
    if (lane == 0) scale[row] = 0.f;
    return;
  }
  const float4* sp = (const float4*)(src + (size_t)row * D_DIM);
  float4 a = sp[2 * lane], b = sp[2 * lane + 1];   // 8 consecutive elements
  float ss = a.x*a.x + a.y*a.y + a.z*a.z + a.w*a.w
           + b.x*b.x + b.y*b.y + b.z*b.z + b.w*b.w;
  float am = fmaxf(fmaxf(fmaxf(fabsf(a.x), fabsf(a.y)),
                         fmaxf(fabsf(a.z), fabsf(a.w))),
                   fmaxf(fmaxf(fabsf(b.x), fabsf(b.y)),
                         fmaxf(fabsf(b.z), fabsf(b.w))));
  #pragma unroll
  for (int off = 1; off < 64; off <<= 1) {
    ss += __shfl_xor(ss, off);
    am = fmaxf(am, __shfl_xor(am, off));
  }
  am = fmaxf(am, 1e-30f);
  float iv = 1.0f / fmaxf(sqrtf(ss), 1e-12f);
  float qs = 127.0f / am;
  if (lane == 0) { inv[row] = iv; scale[row] = am * iv * (1.0f / 127.0f); }
  uint2 o;
  o.x = pk4(a.x, a.y, a.z, a.w, qs);
  o.y = pk4(b.x, b.y, b.z, b.w, qs);
  ((uint2*)(dst + (size_t)row * D_DIM))[lane] = o;
  if (frag) {
    // lane holds k-bytes [8*lane, 8*lane+8): kt = lane>>3, l4 = (lane>>1)&3,
    // 8B-half = lane&1; row -> (g = row>>4, l15 = row&15)
    const int g = row >> 4, l15r = row & 15;
    const size_t db = ((size_t)((g * 8 + (lane >> 3)) * 64
                     + ((lane >> 1) & 3) * 16 + l15r) << 4) + (lane & 1) * 8;
    *(uint2*)(frag + db) = o;
  }
}

// --------------------- i8 GEMM: B panel in LDS, barrier-free K-loop,
// A in FRAGMENT-MAJOR layout -> every A-load is one contiguous 1 KB
// single-segment transaction (r13's 16-segment row-gather eliminated; that
// gather was ~2048 TA-cycles/CU per kt-round — the r13/r15 latency wall).
// Structure otherwise r13 verbatim (proven no-spill): 782 blocks, 4 waves,
// 2 blocks/CU, acc[4][8]=128 AGPR, kt at unroll 1 with 1-deep A prefetch.
__global__ __launch_bounds__(256, 2) void gemm_fused(
    const signed char* __restrict__ Bg,     // nw_q [C_PAD][512] i8
    const signed char* __restrict__ Af,     // ne_qf fragment-major 512 KB
    const float* __restrict__ sa_img, const float* __restrict__ sb_w,
    float* __restrict__ partials)
{
  __shared__ __align__(16) signed char Bq[128 * 512];   // 64 KB
  __shared__ float red[1024];                           // 4 KB

  const int tid  = threadIdx.x;
  const int lane = tid & 63;
  const int w    = tid >> 6;            // 0..3
  const int l15  = lane & 15;
  const int l4   = lane >> 4;
  const int bn   = blockIdx.x;

  // ---- stage panel: 16 rounds x 4 KB. LDS linear dest; source pre-swizzled
  // with the involution d ^= ((d>>9)&7)<<4  (row = d>>9, 16B-slot bits 4-6).
  {
    const signed char* src = Bg + (size_t)bn * (128 * 512);
    #pragma unroll
    for (int i = 0; i < 16; ++i) {
      const int dbase = i * 4096 + w * 1024;     // wave-uniform
      const int d = dbase + lane * 16;           // this lane's dest byte
      const int s = d ^ (((d >> 9) & 7) << 4);
      GLD16(src + s, &Bq[dbase]);
    }
  }
  asm volatile("s_waitcnt vmcnt(0)" ::: "memory");
  __syncthreads();                               // the ONLY barrier pre-store

  const char* Bb = (const char*)Bq;
  const int bswz = (l15 & 7) << 4;

  #pragma unroll 1
  for (int st = 0; st < 4; ++st) {               // 4 stripes of 64 rows
    int4v acc[4][8] = {};                        // 128 AGPRs
    const int g0 = w * 16 + st * 4;              // 16-row fragment groups
    // fragment-major: chunk base for (g, kt) = ((g*8 + kt)*64 + lane) * 16
    const signed char* abase = Af + ((size_t)(g0 * 8 * 64 + lane) << 4);

    int4v afc[4];
    #pragma unroll
    for (int mf = 0; mf < 4; ++mf)
      afc[mf] = *(const int4v*)(abase + (size_t)(mf * 8) * 1024);

    #pragma unroll 1
    for (int kt = 0; kt < 8; ++kt) {
      int4v afn[4];
      if (kt < 7) {                              // prefetch next kt early
        #pragma unroll
        for (int mf = 0; mf < 4; ++mf)
          afn[mf] = *(const int4v*)(abase + (size_t)(mf * 8 + kt + 1) * 1024);
      }
      #pragma unroll
      for (int n = 0; n < 8; ++n) {
        const int byt = (((n * 16 + l15) * 512) + kt * 64 + l4 * 16) ^ bswz;
        int4v bf = *(const int4v*)(Bb + byt);
        #pragma unroll
        for (int mf = 0; mf < 4; ++mf)
          acc[mf][n] = __builtin_amdgcn_mfma_i32_16x16x64_i8(
              afc[mf], bf, acc[mf][n], 0, 0, 0);
      }
      if (kt < 7) {
        #pragma unroll
        for (int mf = 0; mf < 4; ++mf) afc[mf] = afn[mf];
      }
    }

    // stripe epilogue: dequant + exp2 + DPP reduce -> red[] (unique rows)
    // C/D layout (m89, dtype-independent): col = l15, row_in_frag = l4*4 + j
    float sb2[8], offc[8];
    #pragma unroll
    for (int n = 0; n < 8; ++n) {
      int gcol = bn * 128 + n * 16 + l15;
      sb2[n]  = sb_w[gcol] * SCALE_LN2;          // sb_w[pad] = 0
      offc[n] = (gcol < C_CLS) ? 0.f : -1e38f;
    }
    const int row0 = w * 256 + st * 64;
    #pragma unroll
    for (int mf = 0; mf < 4; ++mf) {
      #pragma unroll
      for (int j = 0; j < 4; ++j) {
        const int row = row0 + mf * 16 + l4 * 4 + j;
        const float sa = sa_img[row];
        float s = 0.f;
        #pragma unroll
        for (int n = 0; n < 8; ++n) {
          float x = (float)acc[mf][n][j] * sa;
          s += __builtin_amdgcn_exp2f(fmaf(x, sb2[n], offc[n]));
        }
        s = dpp_red<0xB1>(s);   // quad_perm xor1
        s = dpp_red<0x4E>(s);   // quad_perm xor2
        s = dpp_red<0x124>(s);  // row_ror:4
        s = dpp_red<0x128>(s);  // row_ror:8
        if (l15 == 0) red[row] = s;
      }
    }
  }
  __syncthreads();
  #pragma unroll
  for (int t = 0; t < 4; ++t)                    // one dense 4 KB store
    partials[(size_t)bn * 1024 + t * 256 + tid] = red[t * 256 + tid];
}

// ---------------------------------------------------------------- zero rows
__global__ void zero_rows(float* p) {
  p[blockIdx.x * 256 + threadIdx.x] = 0.f;
}

// ------------------- row_sums[r] += partials chunk sums (32 blocks, atomic)
__global__ __launch_bounds__(256) void reduce_partials(
    const float* __restrict__ partials, float* __restrict__ row_sums)
{
  const int c = blockIdx.x >> 2;                  // bn-chunk 0..7
  const int gid = (blockIdx.x & 3) * 256 + threadIdx.x;
  const int b0 = c * 98;
  const int b1 = (b0 + 98 < NPAN) ? b0 + 98 : NPAN;
  float s = 0.f;
  for (int bn = b0; bn < b1; ++bn)
    s += partials[(size_t)bn * 1024 + gid];
  atomicAdd(&row_sums[gid], s);
}

// ---------------------------------------- per-row margin fixup + row loss
// Subtracts the quantized target term BIT-EXACTLY: same i32 dot from the
// stored (linear-layout) q-vectors + the identical float expression as the
// GEMM epilogue.
__global__ __launch_bounds__(256) void fix_loss(
    const float* __restrict__ images, const float* __restrict__ weight,
    const int* __restrict__ labels, const float* __restrict__ img_inv,
    const float* __restrict__ w_inv,
    const signed char* __restrict__ ne_q, const signed char* __restrict__ nw_q,
    const float* __restrict__ sa_img, const float* __restrict__ sb_w,
    const float* __restrict__ row_sums, float* __restrict__ loss_buf)
{
  int row = blockIdx.x * 4 + (threadIdx.x >> 6);
  int lane = threadIdx.x & 63;
  int lab = labels[row];
  const float4* ip = (const float4*)(images + (size_t)row * D_DIM);
  const float4* wp = (const float4*)(weight + (size_t)lab * D_DIM);
  float4 a = ip[lane],       b = wp[lane];
  float4 a2 = ip[lane + 64], b2 = wp[lane + 64];
  float dot = a.x*b.x + a.y*b.y + a.z*b.z + a.w*b.w
            + a2.x*b2.x + a2.y*b2.y + a2.z*b2.z + a2.w*b2.w;
  uint qa0 = ((const uint*)(ne_q + (size_t)row * D_DIM))[lane];
  uint qa1 = ((const uint*)(ne_q + (size_t)row * D_DIM))[64 + lane];
  uint qb0 = ((const uint*)(nw_q + (size_t)lab * D_DIM))[lane];
  uint qb1 = ((const uint*)(nw_q + (size_t)lab * D_DIM))[64 + lane];
  int id = dp8(qa0, qb0) + dp8(qa1, qb1);
  #pragma unroll
  for (int off = 1; off < 64; off <<= 1) {
    dot += __shfl_xor(dot, off);
    id  += __shfl_xor(id, off);
  }
  if (lane == 0) {
    // quantized target logit — identical expression to GEMM epilogue
    float x  = (float)id * sa_img[row];
    float eq = __builtin_amdgcn_exp2f(fmaf(x, sb_w[lab] * SCALE_LN2, 0.f));
    // f32-exact target cosine + ArcFace margin
    float t = dot * img_inv[row] * w_inv[lab];
    t = fminf(fmaxf(t, -1.f), 1.f);
    float tadj = t * COS_M - sqrtf(fmaxf(1.f - t * t, 0.f)) * SIN_M;
    float s = row_sums[row] - eq
            + __builtin_amdgcn_exp2f(tadj * SCALE_LN2);
    loss_buf[row] = logf(s) - 64.f * tadj;
  }
}

// ------------------------------------------------------------ final mean
__global__ void final_reduce(const float* __restrict__ loss_buf,
                             float* __restrict__ out)
{
  __shared__ float sh[16];
  int tid = threadIdx.x;
  float v = loss_buf[tid];
  #pragma unroll
  for (int off = 1; off < 64; off <<= 1) v += __shfl_xor(v, off);
  if ((tid & 63) == 0) sh[tid >> 6] = v;
  __syncthreads();
  if (tid < 16) {
    float w = sh[tid];
    #pragma unroll
    for (int off = 1; off < 16; off <<= 1) w += __shfl_xor(w, off);
    if (tid == 0) out[0] = w * (1.0f / 1024.0f);
  }
}

// ----------------------------------------------------------------- launch
extern "C" void kernel_launch(void* const* d_in, const int* in_sizes, int n_in,
                              void* d_out, int out_size, void* d_ws, size_t ws_size,
                              hipStream_t stream) {
  const float* images = (const float*)d_in[0];
  const int*   labels = (const int*)d_in[1];
  const float* weight = (const float*)d_in[2];
  float* out = (float*)d_out;
  char* ws = (char*)d_ws;

  // workspace layout (512B-aligned offsets)
  float*       row_sums = (float*)(ws + 0);          //  4 KB
  float*       loss_buf = (float*)(ws + 4096);       //  4 KB
  float*       img_inv  = (float*)(ws + 8192);       //  4 KB
  float*       sa_img   = (float*)(ws + 12288);      //  4 KB
  float*       w_inv    = (float*)(ws + 16384);      //  ~400 KB (C_PAD)
  float*       sb_w     = (float*)(ws + 417792);     //  ~400 KB (C_PAD)
  float*       partials = (float*)(ws + 819200);     //  ~3.2 MB [782][1024]
  signed char* ne_q     = (signed char*)(ws + 4022272);  // 512 KB linear
  signed char* ne_qf    = (signed char*)(ws + 4546560);  // 512 KB frag-major
  signed char* nw_q     = (signed char*)(ws + 5070848);  // ~51 MB [C_PAD][512]

  norm_q<<<N_IMG / 4, 256, 0, stream>>>(images, ne_q, ne_qf, sa_img, img_inv,
                                        N_IMG, N_IMG);
  norm_q<<<C_PAD / 4, 256, 0, stream>>>(weight, nw_q, (signed char*)nullptr,
                                        sb_w, w_inv, C_CLS, C_PAD);
  zero_rows<<<4, 256, 0, stream>>>(row_sums);
  gemm_fused<<<NPAN, 256, 0, stream>>>(nw_q, ne_qf, sa_img, sb_w, partials);
  reduce_partials<<<32, 256, 0, stream>>>(partials, row_sums);
  fix_loss<<<N_IMG / 4, 256, 0, stream>>>(images, weight, labels, img_inv,
                                          w_inv, ne_q, nw_q, sa_img, sb_w,
                                          row_sums, loss_buf);
  final_reduce<<<1, 1024, 0, stream>>>(loss_buf, out);
}

// Round 17
// 147.510 us; speedup vs baseline: 1.4438x; 1.0377x over previous
//
#include <hip/hip_runtime.h>
#include <cstdint>

#define N_IMG 1024
#define D_DIM 512
#define C_CLS 100000
#define C_PAD 100096            // 782 * 128
#define NPAN 782                // 128-col B panels
#define SCALE_LN2 92.33248261689366f  // 64 / ln(2)
#define COS_M 0.8775825618903728f
#define SIN_M 0.479425538604203f

typedef __attribute__((ext_vector_type(4))) int int4v;

static __device__ __forceinline__ uint pk4(float a, float b, float c, float d,
                                           float qs) {
  int ia = (int)rintf(a * qs), ib = (int)rintf(b * qs);
  int ic = (int)rintf(c * qs), id = (int)rintf(d * qs);
  return (ia & 255) | ((ib & 255) << 8) | ((ic & 255) << 16) | ((id & 255) << 24);
}

static __device__ __forceinline__ int dp8(uint a, uint b) {
  int s = 0;
  #pragma unroll
  for (int i = 0; i < 4; ++i)
    s += (int)(signed char)((a >> (8 * i)) & 255) *
         (int)(signed char)((b >> (8 * i)) & 255);
  return s;
}

// DPP reduction step over 16-lane rows (VALU pipe — no LDS ops)
template <int CTRL>
static __device__ __forceinline__ float dpp_red(float s) {
  int t = __builtin_amdgcn_update_dpp(0, __builtin_bit_cast(int, s),
                                      CTRL, 0xF, 0xF, false);
  return s + __builtin_bit_cast(float, t);
}

// --------------------------- image rows: L2-normalize + int8 quantization
// Dual output: linear (for fix_loss bit-exact recompute) + fragment-major
// (for single-segment GEMM A-loads).
__global__ __launch_bounds__(256) void norm_q(
    const float* __restrict__ src, signed char* __restrict__ dst,
    signed char* __restrict__ frag,
    float* __restrict__ scale, float* __restrict__ inv, int nrows)
{
  int row = blockIdx.x * 4 + (threadIdx.x >> 6);
  int lane = threadIdx.x & 63;
  if (row >= nrows) return;
  const float4* sp = (const float4*)(src + (size_t)row * D_DIM);
  float4 a = sp[2 * lane], b = sp[2 * lane + 1];   // 8 consecutive elements
  float ss = a.x*a.x + a.y*a.y + a.z*a.z + a.w*a.w
           + b.x*b.x + b.y*b.y + b.z*b.z + b.w*b.w;
  float am = fmaxf(fmaxf(fmaxf(fabsf(a.x), fabsf(a.y)),
                         fmaxf(fabsf(a.z), fabsf(a.w))),
                   fmaxf(fmaxf(fabsf(b.x), fabsf(b.y)),
                         fmaxf(fabsf(b.z), fabsf(b.w))));
  #pragma unroll
  for (int off = 1; off < 64; off <<= 1) {
    ss += __shfl_xor(ss, off);
    am = fmaxf(am, __shfl_xor(am, off));
  }
  am = fmaxf(am, 1e-30f);
  float iv = 1.0f / fmaxf(sqrtf(ss), 1e-12f);
  float qs = 127.0f / am;
  if (lane == 0) { inv[row] = iv; scale[row] = am * iv * (1.0f / 127.0f); }
  uint2 o;
  o.x = pk4(a.x, a.y, a.z, a.w, qs);
  o.y = pk4(b.x, b.y, b.z, b.w, qs);
  ((uint2*)(dst + (size_t)row * D_DIM))[lane] = o;
  // fragment-major: chunk (g, kt, l4, l15) = A[g*16+l15][kt*64+l4*16 .. +16)
  const int g = row >> 4, l15r = row & 15;
  const size_t db = ((size_t)((g * 8 + (lane >> 3)) * 64
                   + ((lane >> 1) & 3) * 16 + l15r) << 4) + (lane & 1) * 8;
  *(uint2*)(frag + db) = o;
}

// ------- fused: weight quant (4-row-batched, full-MLP) + i8 GEMM + exp-reduce
// One block per 128-col panel (782 blocks, 256 thr, 4 waves, 2 blocks/CU).
// Phase 1 (r14 failure fixed): wave w quantizes rows w*32..+32 in 8 BATCHES
//   OF 4 — each batch one contiguous 8 KB read (8 independent float4 loads
//   in flight -> ~16 MB device-wide, full HBM BW) then 4 INDEPENDENT
//   shuffle-reduce chains (ILP). Rows read once (r10 fix). Swizzled 8 B
//   ds_writes. Weights cross HBM exactly once device-wide; nw_q round-trip
//   (51 MB write + 51 MB read) eliminated.
// Phase 2 (r16 verbatim, proven no-spill): barrier-free K-loop, frag-major
//   A (single-segment 1 KB loads), acc[4][8]=128 AGPR, kt unroll 1 + 1-deep
//   prefetch. Quant of late blocks overlaps MFMA of early blocks (m114).
__global__ __launch_bounds__(256, 2) void gemm_fused(
    const float* __restrict__ Wt,           // weight [C,512] f32
    const signed char* __restrict__ Af,     // ne_qf fragment-major 512 KB
    const float* __restrict__ sa_img, float* __restrict__ sb_w,
    float* __restrict__ partials)
{
  __shared__ __align__(16) signed char Bq[128 * 512];   // 64 KB
  __shared__ float sb_lds[128];
  __shared__ float red[1024];                           // 4 KB

  const int tid  = threadIdx.x;
  const int lane = tid & 63;
  const int w    = tid >> 6;            // 0..3
  const int l15  = lane & 15;
  const int l4   = lane >> 4;
  const int bn   = blockIdx.x;

  // ---------------- phase 1: panel quantization, 8 batches x 4 rows
  #pragma unroll 1
  for (int b = 0; b < 8; ++b) {
    const int c0 = w * 32 + b * 4;
    float4 va[4], vb[4];
    #pragma unroll
    for (int r = 0; r < 4; ++r) {       // one contiguous 8 KB burst
      const int gr = bn * 128 + c0 + r;
      if (gr < C_CLS) {
        const float4* wp = (const float4*)(Wt + (size_t)gr * D_DIM);
        va[r] = wp[2 * lane]; vb[r] = wp[2 * lane + 1];
      } else {
        va[r].x = va[r].y = va[r].z = va[r].w = 0.f; vb[r] = va[r];
      }
    }
    #pragma unroll
    for (int r = 0; r < 4; ++r) {       // 4 independent reduce chains
      const int c  = c0 + r;
      const int gr = bn * 128 + c;
      float ss = va[r].x*va[r].x + va[r].y*va[r].y + va[r].z*va[r].z
               + va[r].w*va[r].w + vb[r].x*vb[r].x + vb[r].y*vb[r].y
               + vb[r].z*vb[r].z + vb[r].w*vb[r].w;
      float am = fmaxf(fmaxf(fmaxf(fabsf(va[r].x), fabsf(va[r].y)),
                             fmaxf(fabsf(va[r].z), fabsf(va[r].w))),
                       fmaxf(fmaxf(fabsf(vb[r].x), fabsf(vb[r].y)),
                             fmaxf(fabsf(vb[r].z), fabsf(vb[r].w))));
      #pragma unroll
      for (int off = 1; off < 64; off <<= 1) {
        ss += __shfl_xor(ss, off);
        am = fmaxf(am, __shfl_xor(am, off));
      }
      am = fmaxf(am, 1e-30f);
      const float qs = 127.0f / am;
      if (lane == 0)
        sb_lds[c] = (gr < C_CLS)
            ? am * (1.0f / fmaxf(sqrtf(ss), 1e-12f)) * (1.0f / 127.0f) : 0.f;
      uint2 q;
      q.x = pk4(va[r].x, va[r].y, va[r].z, va[r].w, qs);
      q.y = pk4(vb[r].x, vb[r].y, vb[r].z, vb[r].w, qs);
      const int byt = (c * 512 + lane * 8) ^ ((c & 7) << 4);
      *(uint2*)((char*)Bq + byt) = q;
    }
  }
  __syncthreads();                               // the ONLY pre-store barrier

  if (tid < 128) sb_w[bn * 128 + tid] = sb_lds[tid];   // dense 512 B

  const char* Bb = (const char*)Bq;
  const int bswz = (l15 & 7) << 4;

  // ---------------- phase 2: barrier-free K-loop (r16 verbatim)
  #pragma unroll 1
  for (int st = 0; st < 4; ++st) {               // 4 stripes of 64 rows
    int4v acc[4][8] = {};                        // 128 AGPRs
    const int g0 = w * 16 + st * 4;              // 16-row fragment groups
    const signed char* abase = Af + ((size_t)(g0 * 8 * 64 + lane) << 4);

    int4v afc[4];
    #pragma unroll
    for (int mf = 0; mf < 4; ++mf)
      afc[mf] = *(const int4v*)(abase + (size_t)(mf * 8) * 1024);

    #pragma unroll 1
    for (int kt = 0; kt < 8; ++kt) {
      int4v afn[4];
      if (kt < 7) {                              // prefetch next kt early
        #pragma unroll
        for (int mf = 0; mf < 4; ++mf)
          afn[mf] = *(const int4v*)(abase + (size_t)(mf * 8 + kt + 1) * 1024);
      }
      #pragma unroll
      for (int n = 0; n < 8; ++n) {
        const int byt = (((n * 16 + l15) * 512) + kt * 64 + l4 * 16) ^ bswz;
        int4v bf = *(const int4v*)(Bb + byt);
        #pragma unroll
        for (int mf = 0; mf < 4; ++mf)
          acc[mf][n] = __builtin_amdgcn_mfma_i32_16x16x64_i8(
              afc[mf], bf, acc[mf][n], 0, 0, 0);
      }
      if (kt < 7) {
        #pragma unroll
        for (int mf = 0; mf < 4; ++mf) afc[mf] = afn[mf];
      }
    }

    // stripe epilogue: dequant + exp2 + DPP reduce -> red[] (unique rows)
    // C/D layout (m89, dtype-independent): col = l15, row_in_frag = l4*4 + j
    float sb2[8], offc[8];
    #pragma unroll
    for (int n = 0; n < 8; ++n) {
      int gcol = bn * 128 + n * 16 + l15;
      sb2[n]  = sb_lds[n * 16 + l15] * SCALE_LN2;
      offc[n] = (gcol < C_CLS) ? 0.f : -1e38f;
    }
    const int row0 = w * 256 + st * 64;
    #pragma unroll
    for (int mf = 0; mf < 4; ++mf) {
      #pragma unroll
      for (int j = 0; j < 4; ++j) {
        const int row = row0 + mf * 16 + l4 * 4 + j;
        const float sa = sa_img[row];
        float s = 0.f;
        #pragma unroll
        for (int n = 0; n < 8; ++n) {
          float x = (float)acc[mf][n][j] * sa;
          s += __builtin_amdgcn_exp2f(fmaf(x, sb2[n], offc[n]));
        }
        s = dpp_red<0xB1>(s);   // quad_perm xor1
        s = dpp_red<0x4E>(s);   // quad_perm xor2
        s = dpp_red<0x124>(s);  // row_ror:4
        s = dpp_red<0x128>(s);  // row_ror:8
        if (l15 == 0) red[row] = s;
      }
    }
  }
  __syncthreads();
  #pragma unroll
  for (int t = 0; t < 4; ++t)                    // one dense 4 KB store
    partials[(size_t)bn * 1024 + t * 256 + tid] = red[t * 256 + tid];
}

// ---------------------------------------------------------------- zero rows
__global__ void zero_rows(float* p) {
  p[blockIdx.x * 256 + threadIdx.x] = 0.f;
}

// ------------------- row_sums[r] += partials chunk sums (128 blocks, atomic)
__global__ __launch_bounds__(256) void reduce_partials(
    const float* __restrict__ partials, float* __restrict__ row_sums)
{
  const int c = blockIdx.x >> 2;                  // bn-chunk 0..31
  const int gid = (blockIdx.x & 3) * 256 + threadIdx.x;
  const int b0 = c * 25;
  const int b1 = (b0 + 25 < NPAN) ? b0 + 25 : NPAN;
  float s = 0.f;
  for (int bn = b0; bn < b1; ++bn)
    s += partials[(size_t)bn * 1024 + gid];
  atomicAdd(&row_sums[gid], s);
}

// ---------------------------------------- per-row margin fixup + row loss
// Recomputes the label row's weight quantization from f32 BIT-EXACTLY
// (amax via fmax exact & order-independent; qs/pk4 identical math — proven
// r14, absmax 0.0), reads sb_w written by gemm, identical epilogue expr.
__global__ __launch_bounds__(256) void fix_loss(
    const float* __restrict__ images, const float* __restrict__ weight,
    const int* __restrict__ labels, const float* __restrict__ img_inv,
    const signed char* __restrict__ ne_q, const float* __restrict__ sa_img,
    const float* __restrict__ sb_w, const float* __restrict__ row_sums,
    float* __restrict__ loss_buf)
{
  int row = blockIdx.x * 4 + (threadIdx.x >> 6);
  int lane = threadIdx.x & 63;
  int lab = labels[row];
  const float4* ip = (const float4*)(images + (size_t)row * D_DIM);
  const float4* wp = (const float4*)(weight + (size_t)lab * D_DIM);
  float4 a = ip[lane],       b = wp[lane];        // elements [4*lane, +4)
  float4 a2 = ip[lane + 64], b2 = wp[lane + 64];  // elements [256+4*lane, +4)
  float dot = a.x*b.x + a.y*b.y + a.z*b.z + a.w*b.w
            + a2.x*b2.x + a2.y*b2.y + a2.z*b2.z + a2.w*b2.w;
  float ssw = b.x*b.x + b.y*b.y + b.z*b.z + b.w*b.w
            + b2.x*b2.x + b2.y*b2.y + b2.z*b2.z + b2.w*b2.w;
  float am = fmaxf(fmaxf(fmaxf(fabsf(b.x), fabsf(b.y)),
                         fmaxf(fabsf(b.z), fabsf(b.w))),
                   fmaxf(fmaxf(fabsf(b2.x), fabsf(b2.y)),
                         fmaxf(fabsf(b2.z), fabsf(b2.w))));
  #pragma unroll
  for (int off = 1; off < 64; off <<= 1)
    am = fmaxf(am, __shfl_xor(am, off));
  am = fmaxf(am, 1e-30f);
  const float qs = 127.0f / am;
  uint qb0 = pk4(b.x, b.y, b.z, b.w, qs);
  uint qb1 = pk4(b2.x, b2.y, b2.z, b2.w, qs);
  uint qa0 = ((const uint*)(ne_q + (size_t)row * D_DIM))[lane];
  uint qa1 = ((const uint*)(ne_q + (size_t)row * D_DIM))[64 + lane];
  int id = dp8(qa0, qb0) + dp8(qa1, qb1);
  #pragma unroll
  for (int off = 1; off < 64; off <<= 1) {
    dot += __shfl_xor(dot, off);
    ssw += __shfl_xor(ssw, off);
    id  += __shfl_xor(id, off);
  }
  if (lane == 0) {
    // quantized target logit — identical expression to GEMM epilogue
    float x  = (float)id * sa_img[row];
    float eq = __builtin_amdgcn_exp2f(fmaf(x, sb_w[lab] * SCALE_LN2, 0.f));
    // f32-exact target cosine + ArcFace margin
    float ivw = 1.0f / fmaxf(sqrtf(ssw), 1e-12f);
    float t = dot * img_inv[row] * ivw;
    t = fminf(fmaxf(t, -1.f), 1.f);
    float tadj = t * COS_M - sqrtf(fmaxf(1.f - t * t, 0.f)) * SIN_M;
    float s = row_sums[row] - eq
            + __builtin_amdgcn_exp2f(tadj * SCALE_LN2);
    loss_buf[row] = logf(s) - 64.f * tadj;
  }
}

// ------------------------------------------------------------ final mean
__global__ void final_reduce(const float* __restrict__ loss_buf,
                             float* __restrict__ out)
{
  __shared__ float sh[16];
  int tid = threadIdx.x;
  float v = loss_buf[tid];
  #pragma unroll
  for (int off = 1; off < 64; off <<= 1) v += __shfl_xor(v, off);
  if ((tid & 63) == 0) sh[tid >> 6] = v;
  __syncthreads();
  if (tid < 16) {
    float w = sh[tid];
    #pragma unroll
    for (int off = 1; off < 16; off <<= 1) w += __shfl_xor(w, off);
    if (tid == 0) out[0] = w * (1.0f / 1024.0f);
  }
}

// ----------------------------------------------------------------- launch
extern "C" void kernel_launch(void* const* d_in, const int* in_sizes, int n_in,
                              void* d_out, int out_size, void* d_ws, size_t ws_size,
                              hipStream_t stream) {
  const float* images = (const float*)d_in[0];
  const int*   labels = (const int*)d_in[1];
  const float* weight = (const float*)d_in[2];
  float* out = (float*)d_out;
  char* ws = (char*)d_ws;

  // workspace layout (512B-aligned offsets)
  float*       row_sums = (float*)(ws + 0);          //  4 KB
  float*       loss_buf = (float*)(ws + 4096);       //  4 KB
  float*       img_inv  = (float*)(ws + 8192);       //  4 KB
  float*       sa_img   = (float*)(ws + 12288);      //  4 KB
  float*       sb_w     = (float*)(ws + 16384);      //  ~400 KB (C_PAD f32)
  float*       partials = (float*)(ws + 417792);     //  ~3.2 MB [782][1024]
  signed char* ne_q     = (signed char*)(ws + 3622912);  // 512 KB linear
  signed char* ne_qf    = (signed char*)(ws + 4149248);  // 512 KB frag-major

  norm_q<<<N_IMG / 4, 256, 0, stream>>>(images, ne_q, ne_qf, sa_img, img_inv,
                                        N_IMG);
  zero_rows<<<4, 256, 0, stream>>>(row_sums);
  gemm_fused<<<NPAN, 256, 0, stream>>>(weight, ne_qf, sa_img, sb_w, partials);
  reduce_partials<<<128, 256, 0, stream>>>(partials, row_sums);
  fix_loss<<<N_IMG / 4, 256, 0, stream>>>(images, weight, labels, img_inv,
                                          ne_q, sa_img, sb_w,
                                          row_sums, loss_buf);
  final_reduce<<<1, 1024, 0, stream>>>(loss_buf, out);
}

// Round 18
// 127.634 us; speedup vs baseline: 1.6686x; 1.1557x over previous
//
#include <hip/hip_runtime.h>
#include <cstdint>

#define N_IMG 1024
#define D_DIM 512
#define C_CLS 100000
#define C_PAD 100096            // 1564 * 64
#define NPAN 1564               // 64-col B panels
#define SCALE_LN2 92.33248261689366f  // 64 / ln(2)
#define COS_M 0.8775825618903728f
#define SIN_M 0.479425538604203f

typedef __attribute__((ext_vector_type(4))) int int4v;

static __device__ __forceinline__ uint pk4(float a, float b, float c, float d,
                                           float qs) {
  int ia = (int)rintf(a * qs), ib = (int)rintf(b * qs);
  int ic = (int)rintf(c * qs), id = (int)rintf(d * qs);
  return (ia & 255) | ((ib & 255) << 8) | ((ic & 255) << 16) | ((id & 255) << 24);
}

static __device__ __forceinline__ int dp8(uint a, uint b) {
  int s = 0;
  #pragma unroll
  for (int i = 0; i < 4; ++i)
    s += (int)(signed char)((a >> (8 * i)) & 255) *
         (int)(signed char)((b >> (8 * i)) & 255);
  return s;
}

// DPP reduction step over 16-lane rows (VALU pipe — no LDS ops)
template <int CTRL>
static __device__ __forceinline__ float dpp_red(float s) {
  int t = __builtin_amdgcn_update_dpp(0, __builtin_bit_cast(int, s),
                                      CTRL, 0xF, 0xF, false);
  return s + __builtin_bit_cast(float, t);
}

// --------------------------- image rows: L2-normalize + int8 quantization
// Dual output: linear (for fix_loss bit-exact recompute) + fragment-major
// (for single-segment GEMM A-loads).
__global__ __launch_bounds__(256) void norm_q(
    const float* __restrict__ src, signed char* __restrict__ dst,
    signed char* __restrict__ frag,
    float* __restrict__ scale, float* __restrict__ inv, int nrows)
{
  int row = blockIdx.x * 4 + (threadIdx.x >> 6);
  int lane = threadIdx.x & 63;
  if (row >= nrows) return;
  const float4* sp = (const float4*)(src + (size_t)row * D_DIM);
  float4 a = sp[2 * lane], b = sp[2 * lane + 1];   // 8 consecutive elements
  float ss = a.x*a.x + a.y*a.y + a.z*a.z + a.w*a.w
           + b.x*b.x + b.y*b.y + b.z*b.z + b.w*b.w;
  float am = fmaxf(fmaxf(fmaxf(fabsf(a.x), fabsf(a.y)),
                         fmaxf(fabsf(a.z), fabsf(a.w))),
                   fmaxf(fmaxf(fabsf(b.x), fabsf(b.y)),
                         fmaxf(fabsf(b.z), fabsf(b.w))));
  #pragma unroll
  for (int off = 1; off < 64; off <<= 1) {
    ss += __shfl_xor(ss, off);
    am = fmaxf(am, __shfl_xor(am, off));
  }
  am = fmaxf(am, 1e-30f);
  float iv = 1.0f / fmaxf(sqrtf(ss), 1e-12f);
  float qs = 127.0f / am;
  if (lane == 0) { inv[row] = iv; scale[row] = am * iv * (1.0f / 127.0f); }
  uint2 o;
  o.x = pk4(a.x, a.y, a.z, a.w, qs);
  o.y = pk4(b.x, b.y, b.z, b.w, qs);
  ((uint2*)(dst + (size_t)row * D_DIM))[lane] = o;
  // fragment-major: chunk (g, kt, l4, l15) = A[g*16+l15][kt*64+l4*16 .. +16)
  const int g = row >> 4, l15r = row & 15;
  const size_t db = ((size_t)((g * 8 + (lane >> 3)) * 64
                   + ((lane >> 1) & 3) * 16 + l15r) << 4) + (lane & 1) * 8;
  *(uint2*)(frag + db) = o;
}

// ------ fused: weight quant (in-LDS) + i8 GEMM + exp-reduce, 64-col panels
// 1564 blocks, 256 thr, 4 waves; acc[4][4]=64 AGPR + ~80 VGPR ~= 144 unified
// -> launch_bounds(256,3): 3 waves/SIMD, 3 DESYNCED blocks/CU (37 KB LDS).
// r15's occupancy gain without r15's penalty: A is frag-major (r16), so
// halving the panel no longer doubles TA gather traffic.
// Phase 1: wave w quantizes rows w*16..+16 in 8 batches of 2 (contiguous
//   4 KB bursts; ~12 MB device-wide in flight >> BW*latency; rows read once;
//   low reg pressure). Phase 2: r16's proven no-spill barrier-free K-loop.
__global__ __launch_bounds__(256, 3) void gemm_fused(
    const float* __restrict__ Wt,           // weight [C,512] f32
    const signed char* __restrict__ Af,     // ne_qf fragment-major 512 KB
    const float* __restrict__ sa_img, float* __restrict__ sb_w,
    float* __restrict__ partials)
{
  __shared__ __align__(16) signed char Bq[64 * 512];    // 32 KB
  __shared__ float sb_lds[64];
  __shared__ float red[1024];                           // 4 KB

  const int tid  = threadIdx.x;
  const int lane = tid & 63;
  const int w    = tid >> 6;            // 0..3
  const int l15  = lane & 15;
  const int l4   = lane >> 4;
  const int bn   = blockIdx.x;

  // ---------------- phase 1: panel quantization, 8 batches x 2 rows
  #pragma unroll 1
  for (int b = 0; b < 8; ++b) {
    const int c0 = w * 16 + b * 2;
    float4 va[2], vb[2];
    #pragma unroll
    for (int r = 0; r < 2; ++r) {       // one contiguous 4 KB burst
      const int gr = bn * 64 + c0 + r;
      if (gr < C_CLS) {
        const float4* wp = (const float4*)(Wt + (size_t)gr * D_DIM);
        va[r] = wp[2 * lane]; vb[r] = wp[2 * lane + 1];
      } else {
        va[r].x = va[r].y = va[r].z = va[r].w = 0.f; vb[r] = va[r];
      }
    }
    #pragma unroll
    for (int r = 0; r < 2; ++r) {       // 2 independent reduce chains
      const int c  = c0 + r;
      const int gr = bn * 64 + c;
      float ss = va[r].x*va[r].x + va[r].y*va[r].y + va[r].z*va[r].z
               + va[r].w*va[r].w + vb[r].x*vb[r].x + vb[r].y*vb[r].y
               + vb[r].z*vb[r].z + vb[r].w*vb[r].w;
      float am = fmaxf(fmaxf(fmaxf(fabsf(va[r].x), fabsf(va[r].y)),
                             fmaxf(fabsf(va[r].z), fabsf(va[r].w))),
                       fmaxf(fmaxf(fabsf(vb[r].x), fabsf(vb[r].y)),
                             fmaxf(fabsf(vb[r].z), fabsf(vb[r].w))));
      #pragma unroll
      for (int off = 1; off < 64; off <<= 1) {
        ss += __shfl_xor(ss, off);
        am = fmaxf(am, __shfl_xor(am, off));
      }
      am = fmaxf(am, 1e-30f);
      const float qs = 127.0f / am;
      if (lane == 0)
        sb_lds[c] = (gr < C_CLS)
            ? am * (1.0f / fmaxf(sqrtf(ss), 1e-12f)) * (1.0f / 127.0f) : 0.f;
      uint2 q;
      q.x = pk4(va[r].x, va[r].y, va[r].z, va[r].w, qs);
      q.y = pk4(vb[r].x, vb[r].y, vb[r].z, vb[r].w, qs);
      const int byt = (c * 512 + lane * 8) ^ ((c & 7) << 4);
      *(uint2*)((char*)Bq + byt) = q;
    }
  }
  __syncthreads();                               // the ONLY pre-store barrier

  if (tid < 64) sb_w[bn * 64 + tid] = sb_lds[tid];     // dense 256 B

  const char* Bb = (const char*)Bq;
  const int bswz = (l15 & 7) << 4;

  // ---------------- phase 2: barrier-free K-loop (r16 structure, n=0..3)
  #pragma unroll 1
  for (int st = 0; st < 4; ++st) {               // 4 stripes of 64 rows
    int4v acc[4][4] = {};                        // 64 AGPRs
    const int g0 = w * 16 + st * 4;              // 16-row fragment groups
    const signed char* abase = Af + ((size_t)(g0 * 8 * 64 + lane) << 4);

    int4v afc[4];
    #pragma unroll
    for (int mf = 0; mf < 4; ++mf)
      afc[mf] = *(const int4v*)(abase + (size_t)(mf * 8) * 1024);

    #pragma unroll 1
    for (int kt = 0; kt < 8; ++kt) {
      int4v afn[4];
      if (kt < 7) {                              // prefetch next kt early
        #pragma unroll
        for (int mf = 0; mf < 4; ++mf)
          afn[mf] = *(const int4v*)(abase + (size_t)(mf * 8 + kt + 1) * 1024);
      }
      #pragma unroll
      for (int n = 0; n < 4; ++n) {
        const int byt = (((n * 16 + l15) * 512) + kt * 64 + l4 * 16) ^ bswz;
        int4v bf = *(const int4v*)(Bb + byt);
        #pragma unroll
        for (int mf = 0; mf < 4; ++mf)
          acc[mf][n] = __builtin_amdgcn_mfma_i32_16x16x64_i8(
              afc[mf], bf, acc[mf][n], 0, 0, 0);
      }
      if (kt < 7) {
        #pragma unroll
        for (int mf = 0; mf < 4; ++mf) afc[mf] = afn[mf];
      }
    }

    // stripe epilogue: dequant + exp2 + DPP reduce -> red[] (unique rows)
    // C/D layout (m89, dtype-independent): col = l15, row_in_frag = l4*4 + j
    float sb2[4], offc[4];
    #pragma unroll
    for (int n = 0; n < 4; ++n) {
      int gcol = bn * 64 + n * 16 + l15;
      sb2[n]  = sb_lds[n * 16 + l15] * SCALE_LN2;
      offc[n] = (gcol < C_CLS) ? 0.f : -1e38f;
    }
    const int row0 = w * 256 + st * 64;
    #pragma unroll
    for (int mf = 0; mf < 4; ++mf) {
      #pragma unroll
      for (int j = 0; j < 4; ++j) {
        const int row = row0 + mf * 16 + l4 * 4 + j;
        const float sa = sa_img[row];
        float s = 0.f;
        #pragma unroll
        for (int n = 0; n < 4; ++n) {
          float x = (float)acc[mf][n][j] * sa;
          s += __builtin_amdgcn_exp2f(fmaf(x, sb2[n], offc[n]));
        }
        s = dpp_red<0xB1>(s);   // quad_perm xor1
        s = dpp_red<0x4E>(s);   // quad_perm xor2
        s = dpp_red<0x124>(s);  // row_ror:4
        s = dpp_red<0x128>(s);  // row_ror:8
        if (l15 == 0) red[row] = s;
      }
    }
  }
  __syncthreads();
  #pragma unroll
  for (int t = 0; t < 4; ++t)                    // one dense 4 KB store
    partials[(size_t)bn * 1024 + t * 256 + tid] = red[t * 256 + tid];
}

// ---------------------------------------------------------------- zero rows
__global__ void zero_rows(float* p) {
  p[blockIdx.x * 256 + threadIdx.x] = 0.f;
}

// ------------------- row_sums[r] += partials chunk sums (128 blocks, atomic)
__global__ __launch_bounds__(256) void reduce_partials(
    const float* __restrict__ partials, float* __restrict__ row_sums)
{
  const int c = blockIdx.x >> 2;                  // bn-chunk 0..31
  const int gid = (blockIdx.x & 3) * 256 + threadIdx.x;
  const int b0 = c * 49;
  const int b1 = (b0 + 49 < NPAN) ? b0 + 49 : NPAN;
  float s = 0.f;
  for (int bn = b0; bn < b1; ++bn)
    s += partials[(size_t)bn * 1024 + gid];
  atomicAdd(&row_sums[gid], s);
}

// ---------------------------------------- per-row margin fixup + row loss
// Recomputes the label row's weight quantization from f32 BIT-EXACTLY
// (amax via fmax exact & order-independent; qs/pk4 identical math — proven
// r14/r17, absmax 0.0), reads sb_w written by gemm, identical epilogue expr.
__global__ __launch_bounds__(256) void fix_loss(
    const float* __restrict__ images, const float* __restrict__ weight,
    const int* __restrict__ labels, const float* __restrict__ img_inv,
    const signed char* __restrict__ ne_q, const float* __restrict__ sa_img,
    const float* __restrict__ sb_w, const float* __restrict__ row_sums,
    float* __restrict__ loss_buf)
{
  int row = blockIdx.x * 4 + (threadIdx.x >> 6);
  int lane = threadIdx.x & 63;
  int lab = labels[row];
  const float4* ip = (const float4*)(images + (size_t)row * D_DIM);
  const float4* wp = (const float4*)(weight + (size_t)lab * D_DIM);
  float4 a = ip[lane],       b = wp[lane];        // elements [4*lane, +4)
  float4 a2 = ip[lane + 64], b2 = wp[lane + 64];  // elements [256+4*lane, +4)
  float dot = a.x*b.x + a.y*b.y + a.z*b.z + a.w*b.w
            + a2.x*b2.x + a2.y*b2.y + a2.z*b2.z + a2.w*b2.w;
  float ssw = b.x*b.x + b.y*b.y + b.z*b.z + b.w*b.w
            + b2.x*b2.x + b2.y*b2.y + b2.z*b2.z + b2.w*b2.w;
  float am = fmaxf(fmaxf(fmaxf(fabsf(b.x), fabsf(b.y)),
                         fmaxf(fabsf(b.z), fabsf(b.w))),
                   fmaxf(fmaxf(fabsf(b2.x), fabsf(b2.y)),
                         fmaxf(fabsf(b2.z), fabsf(b2.w))));
  #pragma unroll
  for (int off = 1; off < 64; off <<= 1)
    am = fmaxf(am, __shfl_xor(am, off));
  am = fmaxf(am, 1e-30f);
  const float qs = 127.0f / am;
  uint qb0 = pk4(b.x, b.y, b.z, b.w, qs);
  uint qb1 = pk4(b2.x, b2.y, b2.z, b2.w, qs);
  uint qa0 = ((const uint*)(ne_q + (size_t)row * D_DIM))[lane];
  uint qa1 = ((const uint*)(ne_q + (size_t)row * D_DIM))[64 + lane];
  int id = dp8(qa0, qb0) + dp8(qa1, qb1);
  #pragma unroll
  for (int off = 1; off < 64; off <<= 1) {
    dot += __shfl_xor(dot, off);
    ssw += __shfl_xor(ssw, off);
    id  += __shfl_xor(id, off);
  }
  if (lane == 0) {
    // quantized target logit — identical expression to GEMM epilogue
    float x  = (float)id * sa_img[row];
    float eq = __builtin_amdgcn_exp2f(fmaf(x, sb_w[lab] * SCALE_LN2, 0.f));
    // f32-exact target cosine + ArcFace margin
    float ivw = 1.0f / fmaxf(sqrtf(ssw), 1e-12f);
    float t = dot * img_inv[row] * ivw;
    t = fminf(fmaxf(t, -1.f), 1.f);
    float tadj = t * COS_M - sqrtf(fmaxf(1.f - t * t, 0.f)) * SIN_M;
    float s = row_sums[row] - eq
            + __builtin_amdgcn_exp2f(tadj * SCALE_LN2);
    loss_buf[row] = logf(s) - 64.f * tadj;
  }
}

// ------------------------------------------------------------ final mean
__global__ void final_reduce(const float* __restrict__ loss_buf,
                             float* __restrict__ out)
{
  __shared__ float sh[16];
  int tid = threadIdx.x;
  float v = loss_buf[tid];
  #pragma unroll
  for (int off = 1; off < 64; off <<= 1) v += __shfl_xor(v, off);
  if ((tid & 63) == 0) sh[tid >> 6] = v;
  __syncthreads();
  if (tid < 16) {
    float w = sh[tid];
    #pragma unroll
    for (int off = 1; off < 16; off <<= 1) w += __shfl_xor(w, off);
    if (tid == 0) out[0] = w * (1.0f / 1024.0f);
  }
}

// ----------------------------------------------------------------- launch
extern "C" void kernel_launch(void* const* d_in, const int* in_sizes, int n_in,
                              void* d_out, int out_size, void* d_ws, size_t ws_size,
                              hipStream_t stream) {
  const float* images = (const float*)d_in[0];
  const int*   labels = (const int*)d_in[1];
  const float* weight = (const float*)d_in[2];
  float* out = (float*)d_out;
  char* ws = (char*)d_ws;

  // workspace layout (512B-aligned offsets)
  float*       row_sums = (float*)(ws + 0);          //  4 KB
  float*       loss_buf = (float*)(ws + 4096);       //  4 KB
  float*       img_inv  = (float*)(ws + 8192);       //  4 KB
  float*       sa_img   = (float*)(ws + 12288);      //  4 KB
  float*       sb_w     = (float*)(ws + 16384);      //  ~400 KB (C_PAD f32)
  float*       partials = (float*)(ws + 417792);     //  ~6.4 MB [1564][1024]
  signed char* ne_q     = (signed char*)(ws + 6828032);  // 512 KB linear
  signed char* ne_qf    = (signed char*)(ws + 7354368);  // 512 KB frag-major

  norm_q<<<N_IMG / 4, 256, 0, stream>>>(images, ne_q, ne_qf, sa_img, img_inv,
                                        N_IMG);
  zero_rows<<<4, 256, 0, stream>>>(row_sums);
  gemm_fused<<<NPAN, 256, 0, stream>>>(weight, ne_qf, sa_img, sb_w, partials);
  reduce_partials<<<128, 256, 0, stream>>>(partials, row_sums);
  fix_loss<<<N_IMG / 4, 256, 0, stream>>>(images, weight, labels, img_inv,
                                          ne_q, sa_img, sb_w,
                                          row_sums, loss_buf);
  final_reduce<<<1, 1024, 0, stream>>>(loss_buf, out);
}